// Round 18
// baseline (11873.309 us; speedup 1.0000x reference)
//
#include <hip/hip_runtime.h>
#include <math.h>

#define HID 64
#define NCLS 20
#define EPS_CLS 1e-5f
#define EPS_AL 1e-6f
#define TILE 256
#define NCMAX 10240
#define MAXMARK 192

__device__ __forceinline__ float relu_(float x){ return x > 0.f ? x : 0.f; }

__device__ __forceinline__ float pin(float v){
  asm volatile("" : "+v"(v));
  return v;
}
__device__ __forceinline__ float mulrn_b(float a, float b){ return pin(__fmul_rn(a,b)); }
__device__ __forceinline__ float addrn_b(float a, float b){ return pin(__fadd_rn(a,b)); }
__device__ __forceinline__ float subrn_b(float a, float b){ return pin(__fsub_rn(a,b)); }

__device__ __forceinline__ float np_norm2(float x, float y, float z){
  return addrn_b(addrn_b(mulrn_b(x,x), mulrn_b(y,y)), mulrn_b(z,z));
}

// exact numpy-twin lattice d2 for query (qx,qy,qz; n2) vs candidate (cx,cy,cz)
__device__ __forceinline__ float lattice_d2(float qx, float qy, float qz, float n2,
                                            float cx, float cy, float cz, float m2){
  float p0  = mulrn_b(qx, cx);
  float dot = pin(fmaf(qz, cz, fmaf(qy, cy, p0)));
  float nm  = addrn_b(n2, m2);
  float t2d = mulrn_b(2.0f, dot);
  return subrn_b(nm, t2d);
}

// ---------------- Kernel A: conv_cls head (unchanged, passes) ----------------
__global__ void __launch_bounds__(64) cls_head_kernel(
    const float* __restrict__ feats, const float* __restrict__ w1,
    const float* __restrict__ bn_g, const float* __restrict__ bn_b,
    const float* __restrict__ bn_m, const float* __restrict__ bn_v,
    const float* __restrict__ w2, const float* __restrict__ b2,
    float* __restrict__ out, int R)
{
  __shared__ float s1[HID], t1[HID];
  int tx = threadIdx.x;
  if (tx < HID) {
    float s = bn_g[tx] / sqrtf(bn_v[tx] + EPS_CLS);
    s1[tx] = s;
    t1[tx] = bn_b[tx] - bn_m[tx] * s;
  }
  __syncthreads();
  int r = blockIdx.x * 64 + tx;
  if (r >= R) return;
  float x[HID];
  const float4* xr = (const float4*)(feats + (size_t)r * HID);
  #pragma unroll
  for (int i = 0; i < 16; i++) {
    float4 t = xr[i];
    x[4*i+0]=t.x; x[4*i+1]=t.y; x[4*i+2]=t.z; x[4*i+3]=t.w;
  }
  float o[NCLS];
  #pragma unroll
  for (int c = 0; c < NCLS; c++) o[c] = b2[c];
  #pragma unroll
  for (int j = 0; j < HID; j++) {
    float acc = 0.f;
    #pragma unroll
    for (int k = 0; k < HID; k++) acc = fmaf(x[k], w1[k*HID + j], acc);
    float h = relu_(acc * s1[j] + t1[j]);
    #pragma unroll
    for (int c = 0; c < NCLS; c++) o[c] = fmaf(h, w2[j*NCLS + c], o[c]);
  }
  float4* op = (float4*)(out + (size_t)r * NCLS);
  #pragma unroll
  for (int i = 0; i < 5; i++) op[i] = make_float4(o[4*i], o[4*i+1], o[4*i+2], o[4*i+3]);
}

// ---------------- Kernel B1: global 3-NN scan + boundary-tie detection ----------------
__global__ void __launch_bounds__(256) knn_global_kernel(
    const float4* __restrict__ coords, const float4* __restrict__ pts,
    float* __restrict__ wd, int* __restrict__ wi,
    int* __restrict__ mark_cnt, int* __restrict__ mark_rows,
    int NC, int NP)
{
  int frame = blockIdx.z;
  int tx    = threadIdx.x;
  int q     = blockIdx.x * 256 + tx;

  float qx=0.f, qy=0.f, qz=0.f, n2=0.f;
  if (q < NP) {
    float4 p = pts[(size_t)frame * NP + q];
    qx=p.y; qy=p.z; qz=p.w;
    n2 = np_norm2(qx,qy,qz);
  }
  float bd0=1e30f, bd1=1e30f, bd2=1e30f, bd3=1e30f;
  int   bi0=0, bi1=0, bi2=0;

  __shared__ float4 tile[TILE];
  for (int t = 0; t < NC; t += TILE) {
    int n = min(TILE, NC - t);
    if (tx < n) {
      float4 cr = coords[(size_t)frame * NC + t + tx];
      tile[tx] = make_float4(cr.y, cr.z, cr.w, np_norm2(cr.y, cr.z, cr.w));
    }
    __syncthreads();
    for (int j = 0; j < n; j++) {
      float4 c = tile[j];
      float d2 = lattice_d2(qx,qy,qz,n2, c.x,c.y,c.z,c.w);
      if (d2 <= bd3) {
        int ci = t + j;
        if (d2 <= bd1) {
          bd3 = bd2;
          if (d2 <= bd0) { bd2=bd1; bi2=bi1; bd1=bd0; bi1=bi0; bd0=d2; bi0=ci; }
          else           { bd2=bd1; bi2=bi1; bd1=d2;  bi1=ci; }
        } else {
          if (d2 <= bd2) { bd3=bd2; bd2=d2; bi2=ci; }
          else           { bd3=d2; }
        }
      }
    }
    __syncthreads();
  }
  if (q < NP) {
    size_t base = (size_t)(frame * NP + q) * 3;
    wd[base+0]=bd0; wd[base+1]=bd1; wd[base+2]=bd2;
    wi[base+0]=bi0; wi[base+1]=bi1; wi[base+2]=bi2;
    if (bd2 == bd3) {              // exact lattice tie at the set boundary
      int slot = atomicAdd(mark_cnt, 1);
      if (slot < MAXMARK) mark_rows[slot] = frame * NP + q;
    }
  }
}

// ---------------- numpy aquicksort (introsort) — faithful port ----------------
// Indices co-swapped with values (vperm[p] == v[tosort[p]] invariant) — identical
// tie semantics to numpy's index-only sort. SMALL_QUICKSORT=15, med3 pivot,
// larger partition deferred, depth=2*msb(n). Heapsort fallback unreachable here.
#define QSW(i,j) { float fv=v[i]; v[i]=v[j]; v[j]=fv; unsigned short uv=t[i]; t[i]=t[j]; t[j]=uv; }
__device__ void np_aquicksort(float* v, unsigned short* t, int num)
{
  int slo[110], shi[110], sde[110];
  int sp = 0;
  int pl = 0, pr = num - 1;
  int cdepth = (31 - __clz((unsigned)num)) * 2;
  for (;;) {
    while (pr - pl > 15) {
      int pm = pl + ((pr - pl) >> 1);
      if (v[pm] < v[pl]) QSW(pm, pl);
      if (v[pr] < v[pm]) QSW(pr, pm);
      if (v[pm] < v[pl]) QSW(pm, pl);
      float vp = v[pm];
      int pi = pl, pj = pr - 1;
      QSW(pm, pj);
      for (;;) {
        do { ++pi; } while (v[pi] < vp);
        do { --pj; } while (vp < v[pj]);
        if (pi >= pj) break;
        QSW(pi, pj);
      }
      QSW(pi, pr - 1);
      if (pi - pl < pr - pi) { slo[sp]=pi+1; shi[sp]=pr;   pr = pi - 1; }
      else                   { slo[sp]=pl;   shi[sp]=pi-1; pl = pi + 1; }
      sde[sp] = --cdepth; sp++;
    }
    for (int a = pl + 1; a <= pr; ++a) {
      unsigned short vi = t[a]; float vv = v[a];
      int b = a;
      while (b > pl && vv < v[b-1]) { t[b]=t[b-1]; v[b]=v[b-1]; --b; }
      t[b] = vi; v[b] = vv;
    }
    if (sp == 0) break;
    --sp; pl = slo[sp]; pr = shi[sp]; cdepth = sde[sp];
  }
}

// ---------------- Kernel B1.5: re-resolve tie rows via np.argsort(d2)[:, :3] ----------------
__global__ void __launch_bounds__(256) tie_resort_kernel(
    const float4* __restrict__ coords, const float4* __restrict__ pts,
    const int* __restrict__ mark_cnt, const int* __restrict__ mark_rows,
    float* __restrict__ wd, int* __restrict__ wi, int NC, int NP)
{
  __shared__ float vperm[NCMAX];
  __shared__ unsigned short tosort[NCMAX];
  int cnt = *mark_cnt; if (cnt > MAXMARK) cnt = MAXMARK;
  int b = blockIdx.x;
  if (b >= cnt) return;
  int row = mark_rows[b];
  int frame = row / NP;
  int q = row - frame * NP;
  float4 p = pts[(size_t)frame * NP + q];
  float qx=p.y, qy=p.z, qz=p.w;
  float n2 = np_norm2(qx,qy,qz);
  const float4* C = coords + (size_t)frame * NC;
  for (int i = threadIdx.x; i < NC; i += 256) {
    float4 cr = C[i];
    float m2 = np_norm2(cr.y, cr.z, cr.w);
    vperm[i]  = lattice_d2(qx,qy,qz,n2, cr.y,cr.z,cr.w,m2);
    tosort[i] = (unsigned short)i;
  }
  __syncthreads();
  if (threadIdx.x == 0) {
    np_aquicksort(vperm, tosort, NC);
    size_t base = (size_t)row * 3;
    wd[base+0]=vperm[0];  wd[base+1]=vperm[1];  wd[base+2]=vperm[2];
    wi[base+0]=tosort[0]; wi[base+1]=tosort[1]; wi[base+2]=tosort[2];
  }
}

// ---------------- Kernel B2: np-f32 weights + interpolate + align + out head ----------------
__global__ void __launch_bounds__(64) interp_mlp_kernel(
    const float* __restrict__ feats,
    const float* __restrict__ wd, const int* __restrict__ wi,
    const float* __restrict__ al_w, const float* __restrict__ al_b,
    const float* __restrict__ al_g, const float* __restrict__ al_bb,
    const float* __restrict__ al_m, const float* __restrict__ al_v,
    const float* __restrict__ o_w1,
    const float* __restrict__ o_g, const float* __restrict__ o_bb,
    const float* __restrict__ o_m, const float* __restrict__ o_v,
    const float* __restrict__ o_w2, const float* __restrict__ o_b2,
    float* __restrict__ out, int NC, int NP, int B)
{
  __shared__ float s1[HID], t1[HID], s2[HID], t2[HID];
  int tx = threadIdx.x;
  if (tx < HID) {
    float sa = al_g[tx] / sqrtf(al_v[tx] + EPS_AL);
    s1[tx] = sa;
    t1[tx] = (al_b[tx] - al_m[tx]) * sa + al_bb[tx];
    float so = o_g[tx] / sqrtf(o_v[tx] + EPS_CLS);
    s2[tx] = so;
    t2[tx] = o_bb[tx] - o_m[tx] * so;
  }
  __syncthreads();
  int r = blockIdx.x * 64 + tx;
  if (r >= B * NP) return;
  int frame = r / NP;

  float bd0 = wd[(size_t)r*3+0], bd1 = wd[(size_t)r*3+1], bd2 = wd[(size_t)r*3+2];
  int   bi0 = wi[(size_t)r*3+0], bi1 = wi[(size_t)r*3+1], bi2 = wi[(size_t)r*3+2];

  float w0 = pin(__fdiv_rn(1.0f, addrn_b(fmaxf(bd0, 0.f), 1e-8f)));
  float w1 = pin(__fdiv_rn(1.0f, addrn_b(fmaxf(bd1, 0.f), 1e-8f)));
  float w2 = pin(__fdiv_rn(1.0f, addrn_b(fmaxf(bd2, 0.f), 1e-8f)));
  float wsum = addrn_b(addrn_b(w0, w1), w2);
  w0 = pin(__fdiv_rn(w0, wsum)); w1 = pin(__fdiv_rn(w1, wsum)); w2 = pin(__fdiv_rn(w2, wsum));

  const float* F = feats + (size_t)frame * NC * HID;
  const float4* F0 = (const float4*)(F + (size_t)bi0 * HID);
  const float4* F1 = (const float4*)(F + (size_t)bi1 * HID);
  const float4* F2 = (const float4*)(F + (size_t)bi2 * HID);

  float interp[HID];
  #pragma unroll
  for (int i = 0; i < 16; i++) {
    float4 a = F0[i], b = F1[i], c = F2[i];
    interp[4*i+0] = (a.x*w0 + b.x*w1) + c.x*w2;
    interp[4*i+1] = (a.y*w0 + b.y*w1) + c.y*w2;
    interp[4*i+2] = (a.z*w0 + b.z*w1) + c.z*w2;
    interp[4*i+3] = (a.w*w0 + b.w*w1) + c.w*w2;
  }

  float f[HID];
  #pragma unroll
  for (int j = 0; j < HID; j++) {
    float acc = 0.f;
    #pragma unroll
    for (int k = 0; k < HID; k++) acc = fmaf(interp[k], al_w[k*HID + j], acc);
    f[j] = relu_(acc * s1[j] + t1[j]);
  }
  float o[NCLS];
  #pragma unroll
  for (int c = 0; c < NCLS; c++) o[c] = o_b2[c];
  #pragma unroll
  for (int j = 0; j < HID; j++) {
    float acc = 0.f;
    #pragma unroll
    for (int k = 0; k < HID; k++) acc = fmaf(f[k], o_w1[k*HID + j], acc);
    float h = relu_(acc * s2[j] + t2[j]);
    #pragma unroll
    for (int c = 0; c < NCLS; c++) o[c] = fmaf(h, o_w2[j*NCLS + c], o[c]);
  }
  float4* op = (float4*)(out + (size_t)r * NCLS);
  #pragma unroll
  for (int i = 0; i < 5; i++) op[i] = make_float4(o[4*i], o[4*i+1], o[4*i+2], o[4*i+3]);
}

extern "C" void kernel_launch(void* const* d_in, const int* in_sizes, int n_in,
                              void* d_out, int out_size, void* d_ws, size_t ws_size,
                              hipStream_t stream)
{
  const float*  feats  = (const float*) d_in[0];
  const float4* coords = (const float4*)d_in[1];
  const float4* pts    = (const float4*)d_in[2];
  const float* cls_w1 = (const float*)d_in[3];
  const float* cls_g  = (const float*)d_in[4];
  const float* cls_b  = (const float*)d_in[5];
  const float* cls_m  = (const float*)d_in[6];
  const float* cls_v  = (const float*)d_in[7];
  const float* cls_w2 = (const float*)d_in[8];
  const float* cls_b2 = (const float*)d_in[9];
  const float* al_w   = (const float*)d_in[10];
  const float* al_b   = (const float*)d_in[11];
  const float* al_g   = (const float*)d_in[12];
  const float* al_bb  = (const float*)d_in[13];
  const float* al_m   = (const float*)d_in[14];
  const float* al_v   = (const float*)d_in[15];
  const float* o_w1   = (const float*)d_in[16];
  const float* o_g    = (const float*)d_in[17];
  const float* o_bb   = (const float*)d_in[18];
  const float* o_m    = (const float*)d_in[19];
  const float* o_v    = (const float*)d_in[20];
  const float* o_w2   = (const float*)d_in[21];
  const float* o_b2   = (const float*)d_in[22];

  const int B = 2;
  int RC = in_sizes[1] / 4;  int NC = RC / B;
  int RP = in_sizes[2] / 4;  int NP = RP / B;

  // ws layout: [0:16) mark counter | [16 : 16+4*MAXMARK) marked rows |
  //            then wd[RP*3] f32 | wi[RP*3] i32
  int*   mark_cnt  = (int*)d_ws;
  int*   mark_rows = (int*)((char*)d_ws + 16);
  float* wd = (float*)((char*)d_ws + 16 + 4*MAXMARK);
  int*   wi = (int*)((char*)wd + (size_t)RP * 3 * 4);

  hipMemsetAsync(d_ws, 0, 16, stream);

  cls_head_kernel<<<(RC + 63) / 64, 64, 0, stream>>>(
      feats, cls_w1, cls_g, cls_b, cls_m, cls_v, cls_w2, cls_b2,
      (float*)d_out, RC);

  dim3 g1((NP + 255) / 256, 1, B);
  knn_global_kernel<<<g1, 256, 0, stream>>>(coords, pts, wd, wi,
                                            mark_cnt, mark_rows, NC, NP);

  // re-resolve boundary-tie rows with the exact numpy argsort order
  tie_resort_kernel<<<MAXMARK, 256, 0, stream>>>(coords, pts, mark_cnt, mark_rows,
                                                 wd, wi, NC, NP);

  float* out2 = (float*)d_out + (size_t)RC * NCLS;
  interp_mlp_kernel<<<(RP + 63) / 64, 64, 0, stream>>>(
      feats, wd, wi,
      al_w, al_b, al_g, al_bb, al_m, al_v,
      o_w1, o_g, o_bb, o_m, o_v, o_w2, o_b2,
      out2, NC, NP, B);
}

// Round 19
// 1724.868 us; speedup vs baseline: 6.8836x; 6.8836x over previous
//
#include <hip/hip_runtime.h>
#include <math.h>

#define HID 64
#define NCLS 20
#define EPS_CLS 1e-5f
#define EPS_AL 1e-6f
#define NCMAX 10240
#define MAXMARK 192
#define QPB 64      // queries per scan block
#define NCHUNK 4    // candidate chunks per query

__device__ __forceinline__ float relu_(float x){ return x > 0.f ? x : 0.f; }

__device__ __forceinline__ float pin(float v){
  asm volatile("" : "+v"(v));
  return v;
}
__device__ __forceinline__ float mulrn_b(float a, float b){ return pin(__fmul_rn(a,b)); }
__device__ __forceinline__ float addrn_b(float a, float b){ return pin(__fadd_rn(a,b)); }
__device__ __forceinline__ float subrn_b(float a, float b){ return pin(__fsub_rn(a,b)); }

__device__ __forceinline__ float np_norm2(float x, float y, float z){
  return addrn_b(addrn_b(mulrn_b(x,x), mulrn_b(y,y)), mulrn_b(z,z));
}

// exact numpy-twin lattice d2 (verified R18)
__device__ __forceinline__ float lattice_d2(float qx, float qy, float qz, float n2,
                                            float cx, float cy, float cz, float m2){
  float p0  = mulrn_b(qx, cx);
  float dot = pin(fmaf(qz, cz, fmaf(qy, cy, p0)));
  float nm  = addrn_b(n2, m2);
  float t2d = mulrn_b(2.0f, dot);
  return subrn_b(nm, t2d);
}

// ---------------- Kernel A: conv_cls head (unchanged, passes) ----------------
__global__ void __launch_bounds__(64) cls_head_kernel(
    const float* __restrict__ feats, const float* __restrict__ w1,
    const float* __restrict__ bn_g, const float* __restrict__ bn_b,
    const float* __restrict__ bn_m, const float* __restrict__ bn_v,
    const float* __restrict__ w2, const float* __restrict__ b2,
    float* __restrict__ out, int R)
{
  __shared__ float s1[HID], t1[HID];
  int tx = threadIdx.x;
  if (tx < HID) {
    float s = bn_g[tx] / sqrtf(bn_v[tx] + EPS_CLS);
    s1[tx] = s;
    t1[tx] = bn_b[tx] - bn_m[tx] * s;
  }
  __syncthreads();
  int r = blockIdx.x * 64 + tx;
  if (r >= R) return;
  float x[HID];
  const float4* xr = (const float4*)(feats + (size_t)r * HID);
  #pragma unroll
  for (int i = 0; i < 16; i++) {
    float4 t = xr[i];
    x[4*i+0]=t.x; x[4*i+1]=t.y; x[4*i+2]=t.z; x[4*i+3]=t.w;
  }
  float o[NCLS];
  #pragma unroll
  for (int c = 0; c < NCLS; c++) o[c] = b2[c];
  #pragma unroll
  for (int j = 0; j < HID; j++) {
    float acc = 0.f;
    #pragma unroll
    for (int k = 0; k < HID; k++) acc = fmaf(x[k], w1[k*HID + j], acc);
    float h = relu_(acc * s1[j] + t1[j]);
    #pragma unroll
    for (int c = 0; c < NCLS; c++) o[c] = fmaf(h, w2[j*NCLS + c], o[c]);
  }
  float4* op = (float4*)(out + (size_t)r * NCLS);
  #pragma unroll
  for (int i = 0; i < 5; i++) op[i] = make_float4(o[4*i], o[4*i+1], o[4*i+2], o[4*i+3]);
}

// ---------------- Kernel B1: chunked 3-NN scan + in-block merge + tie mark ----------------
// 256 threads = 64 queries x 4 candidate chunks. Wave-uniform candidate loads
// (broadcast from L2). Per-chunk top-4 in registers; LDS merge to global top-4.
// Unmarked rows have a unique top-3 SET (exactly 3 elements <= bd2), so chunk
// tie-rules don't matter; marked rows (bd2==bd3 exact) get the numpy sort.
__global__ void __launch_bounds__(256) knn_scan_kernel(
    const float4* __restrict__ coords, const float4* __restrict__ pts,
    float* __restrict__ wd, int* __restrict__ wi,
    int* __restrict__ mark_cnt, int* __restrict__ mark_rows,
    int NC, int NP)
{
  __shared__ float sd[QPB][NCHUNK][4];
  __shared__ int   si[QPB][NCHUNK][4];
  int frame = blockIdx.z;
  int tx    = threadIdx.x;
  int qid   = tx & (QPB - 1);
  int chunk = tx >> 6;
  int q = blockIdx.x * QPB + qid;
  bool valid = (q < NP);

  float qx=0.f, qy=0.f, qz=0.f, n2=0.f;
  if (valid) {
    float4 p = pts[(size_t)frame * NP + q];
    qx=p.y; qy=p.z; qz=p.w;
    n2 = np_norm2(qx,qy,qz);
  }
  int clen = (NC + NCHUNK - 1) / NCHUNK;
  int c0 = chunk * clen, c1 = min(NC, c0 + clen);
  float d0=1e30f, d1=1e30f, d2v=1e30f, d3=1e30f;
  int   i0=0, i1=0, i2=0, i3=0;
  const float4* C = coords + (size_t)frame * NC;
  for (int j = c0; j < c1; j++) {
    float4 c = C[j];                       // wave-uniform -> broadcast
    float m2 = np_norm2(c.y, c.z, c.w);
    float dd = lattice_d2(qx,qy,qz,n2, c.y,c.z,c.w,m2);
    if (dd < d3) {
      if (dd < d1) {
        if (dd < d0) { d3=d2v;i3=i2; d2v=d1;i2=i1; d1=d0;i1=i0; d0=dd;i0=j; }
        else         { d3=d2v;i3=i2; d2v=d1;i2=i1; d1=dd;i1=j; }
      } else {
        if (dd < d2v){ d3=d2v;i3=i2; d2v=dd;i2=j; }
        else         { d3=dd; i3=j; }
      }
    }
  }
  sd[qid][chunk][0]=d0; sd[qid][chunk][1]=d1; sd[qid][chunk][2]=d2v; sd[qid][chunk][3]=d3;
  si[qid][chunk][0]=i0; si[qid][chunk][1]=i1; si[qid][chunk][2]=i2; si[qid][chunk][3]=i3;
  __syncthreads();
  if (tx < QPB && valid) {
    float m0=1e30f, m1=1e30f, m2v=1e30f, m3=1e30f;
    int   j0=0, j1=0, j2=0;
    #pragma unroll
    for (int c = 0; c < NCHUNK; c++) {
      #pragma unroll
      for (int r = 0; r < 4; r++) {
        float dd = sd[tx][c][r]; int jj = si[tx][c][r];
        if (dd < m3) {
          if (dd < m1) {
            if (dd < m0) { m3=m2v; m2v=m1;j2=j1; m1=m0;j1=j0; m0=dd;j0=jj; }
            else         { m3=m2v; m2v=m1;j2=j1; m1=dd;j1=jj; }
          } else {
            if (dd < m2v){ m3=m2v; m2v=dd;j2=jj; }
            else         { m3=dd; }
          }
        }
      }
    }
    int row = frame * NP + q;
    size_t base = (size_t)row * 3;
    wd[base+0]=m0; wd[base+1]=m1; wd[base+2]=m2v;
    wi[base+0]=j0; wi[base+1]=j1; wi[base+2]=j2;
    if (m2v == m3) {                   // exact lattice tie at the set boundary
      int slot = atomicAdd(mark_cnt, 1);
      if (slot < MAXMARK) mark_rows[slot] = row;
    }
  }
}

// ---------------- numpy aquicksort, PRUNED to final positions 0..3 ----------------
// Partitions are index-disjoint: a range entirely right of index 3 can never
// move elements into [0..3], so it is skipped. Bit-identical head of the sort.
#define QSW(i,j) { float fv=v[i]; v[i]=v[j]; v[j]=fv; unsigned short uv=t[i]; t[i]=t[j]; t[j]=uv; }
__device__ void np_aquicksort_head(float* v, unsigned short* t, int num)
{
  int slo[110], shi[110];
  int sp = 0;
  int pl = 0, pr = num - 1;
  for (;;) {
    bool doins = true;
    while (pr - pl > 15) {
      int pm = pl + ((pr - pl) >> 1);
      if (v[pm] < v[pl]) QSW(pm, pl);
      if (v[pr] < v[pm]) QSW(pr, pm);
      if (v[pm] < v[pl]) QSW(pm, pl);
      float vp = v[pm];
      int pi = pl, pj = pr - 1;
      QSW(pm, pj);
      for (;;) {
        do { ++pi; } while (v[pi] < vp);
        do { --pj; } while (vp < v[pj]);
        if (pi >= pj) break;
        QSW(pi, pj);
      }
      QSW(pi, pr - 1);
      if (pi - pl < pr - pi) {
        if (pi + 1 <= 3) { slo[sp]=pi+1; shi[sp]=pr; sp++; }  // prune right push
        pr = pi - 1;
      } else {
        slo[sp]=pl; shi[sp]=pi-1; sp++;                       // lo=pl<=3 always
        pl = pi + 1;
        if (pl > 3) { doins = false; break; }                  // prune continue
      }
    }
    if (doins) {
      for (int a = pl + 1; a <= pr; ++a) {
        unsigned short vi = t[a]; float vv = v[a];
        int b = a;
        while (b > pl && vv < v[b-1]) { t[b]=t[b-1]; v[b]=v[b-1]; --b; }
        t[b] = vi; v[b] = vv;
      }
    }
    if (sp == 0) break;
    --sp; pl = slo[sp]; pr = shi[sp];
  }
}

// ---------------- Kernel B1.5: re-resolve tie rows via np.argsort(d2)[:, :3] ----------------
__global__ void __launch_bounds__(256) tie_resort_kernel(
    const float4* __restrict__ coords, const float4* __restrict__ pts,
    const int* __restrict__ mark_cnt, const int* __restrict__ mark_rows,
    float* __restrict__ wd, int* __restrict__ wi, int NC, int NP)
{
  __shared__ float vperm[NCMAX];
  __shared__ unsigned short tosort[NCMAX];
  int cnt = *mark_cnt; if (cnt > MAXMARK) cnt = MAXMARK;
  int b = blockIdx.x;
  if (b >= cnt) return;
  int row = mark_rows[b];
  int frame = row / NP;
  int q = row - frame * NP;
  float4 p = pts[(size_t)frame * NP + q];
  float qx=p.y, qy=p.z, qz=p.w;
  float n2 = np_norm2(qx,qy,qz);
  const float4* C = coords + (size_t)frame * NC;
  for (int i = threadIdx.x; i < NC; i += 256) {
    float4 cr = C[i];
    float m2 = np_norm2(cr.y, cr.z, cr.w);
    vperm[i]  = lattice_d2(qx,qy,qz,n2, cr.y,cr.z,cr.w,m2);
    tosort[i] = (unsigned short)i;
  }
  __syncthreads();
  if (threadIdx.x == 0) {
    np_aquicksort_head(vperm, tosort, NC);
    size_t base = (size_t)row * 3;
    wd[base+0]=vperm[0];  wd[base+1]=vperm[1];  wd[base+2]=vperm[2];
    wi[base+0]=tosort[0]; wi[base+1]=tosort[1]; wi[base+2]=tosort[2];
  }
}

// ---------------- Kernel B2: np-f32 weights + interpolate + align + out head ----------------
__global__ void __launch_bounds__(64) interp_mlp_kernel(
    const float* __restrict__ feats,
    const float* __restrict__ wd, const int* __restrict__ wi,
    const float* __restrict__ al_w, const float* __restrict__ al_b,
    const float* __restrict__ al_g, const float* __restrict__ al_bb,
    const float* __restrict__ al_m, const float* __restrict__ al_v,
    const float* __restrict__ o_w1,
    const float* __restrict__ o_g, const float* __restrict__ o_bb,
    const float* __restrict__ o_m, const float* __restrict__ o_v,
    const float* __restrict__ o_w2, const float* __restrict__ o_b2,
    float* __restrict__ out, int NC, int NP, int B)
{
  __shared__ float s1[HID], t1[HID], s2[HID], t2[HID];
  int tx = threadIdx.x;
  if (tx < HID) {
    float sa = al_g[tx] / sqrtf(al_v[tx] + EPS_AL);
    s1[tx] = sa;
    t1[tx] = (al_b[tx] - al_m[tx]) * sa + al_bb[tx];
    float so = o_g[tx] / sqrtf(o_v[tx] + EPS_CLS);
    s2[tx] = so;
    t2[tx] = o_bb[tx] - o_m[tx] * so;
  }
  __syncthreads();
  int r = blockIdx.x * 64 + tx;
  if (r >= B * NP) return;
  int frame = r / NP;

  float bd0 = wd[(size_t)r*3+0], bd1 = wd[(size_t)r*3+1], bd2 = wd[(size_t)r*3+2];
  int   bi0 = wi[(size_t)r*3+0], bi1 = wi[(size_t)r*3+1], bi2 = wi[(size_t)r*3+2];

  float w0 = pin(__fdiv_rn(1.0f, addrn_b(fmaxf(bd0, 0.f), 1e-8f)));
  float w1 = pin(__fdiv_rn(1.0f, addrn_b(fmaxf(bd1, 0.f), 1e-8f)));
  float w2 = pin(__fdiv_rn(1.0f, addrn_b(fmaxf(bd2, 0.f), 1e-8f)));
  float wsum = addrn_b(addrn_b(w0, w1), w2);
  w0 = pin(__fdiv_rn(w0, wsum)); w1 = pin(__fdiv_rn(w1, wsum)); w2 = pin(__fdiv_rn(w2, wsum));

  const float* F = feats + (size_t)frame * NC * HID;
  const float4* F0 = (const float4*)(F + (size_t)bi0 * HID);
  const float4* F1 = (const float4*)(F + (size_t)bi1 * HID);
  const float4* F2 = (const float4*)(F + (size_t)bi2 * HID);

  float interp[HID];
  #pragma unroll
  for (int i = 0; i < 16; i++) {
    float4 a = F0[i], b = F1[i], c = F2[i];
    interp[4*i+0] = (a.x*w0 + b.x*w1) + c.x*w2;
    interp[4*i+1] = (a.y*w0 + b.y*w1) + c.y*w2;
    interp[4*i+2] = (a.z*w0 + b.z*w1) + c.z*w2;
    interp[4*i+3] = (a.w*w0 + b.w*w1) + c.w*w2;
  }

  float f[HID];
  #pragma unroll
  for (int j = 0; j < HID; j++) {
    float acc = 0.f;
    #pragma unroll
    for (int k = 0; k < HID; k++) acc = fmaf(interp[k], al_w[k*HID + j], acc);
    f[j] = relu_(acc * s1[j] + t1[j]);
  }
  float o[NCLS];
  #pragma unroll
  for (int c = 0; c < NCLS; c++) o[c] = o_b2[c];
  #pragma unroll
  for (int j = 0; j < HID; j++) {
    float acc = 0.f;
    #pragma unroll
    for (int k = 0; k < HID; k++) acc = fmaf(f[k], o_w1[k*HID + j], acc);
    float h = relu_(acc * s2[j] + t2[j]);
    #pragma unroll
    for (int c = 0; c < NCLS; c++) o[c] = fmaf(h, o_w2[j*NCLS + c], o[c]);
  }
  float4* op = (float4*)(out + (size_t)r * NCLS);
  #pragma unroll
  for (int i = 0; i < 5; i++) op[i] = make_float4(o[4*i], o[4*i+1], o[4*i+2], o[4*i+3]);
}

extern "C" void kernel_launch(void* const* d_in, const int* in_sizes, int n_in,
                              void* d_out, int out_size, void* d_ws, size_t ws_size,
                              hipStream_t stream)
{
  const float*  feats  = (const float*) d_in[0];
  const float4* coords = (const float4*)d_in[1];
  const float4* pts    = (const float4*)d_in[2];
  const float* cls_w1 = (const float*)d_in[3];
  const float* cls_g  = (const float*)d_in[4];
  const float* cls_b  = (const float*)d_in[5];
  const float* cls_m  = (const float*)d_in[6];
  const float* cls_v  = (const float*)d_in[7];
  const float* cls_w2 = (const float*)d_in[8];
  const float* cls_b2 = (const float*)d_in[9];
  const float* al_w   = (const float*)d_in[10];
  const float* al_b   = (const float*)d_in[11];
  const float* al_g   = (const float*)d_in[12];
  const float* al_bb  = (const float*)d_in[13];
  const float* al_m   = (const float*)d_in[14];
  const float* al_v   = (const float*)d_in[15];
  const float* o_w1   = (const float*)d_in[16];
  const float* o_g    = (const float*)d_in[17];
  const float* o_bb   = (const float*)d_in[18];
  const float* o_m    = (const float*)d_in[19];
  const float* o_v    = (const float*)d_in[20];
  const float* o_w2   = (const float*)d_in[21];
  const float* o_b2   = (const float*)d_in[22];

  const int B = 2;
  int RC = in_sizes[1] / 4;  int NC = RC / B;
  int RP = in_sizes[2] / 4;  int NP = RP / B;

  // ws layout: [0:16) mark counter | [16 : 16+4*MAXMARK) marked rows |
  //            then wd[RP*3] f32 | wi[RP*3] i32
  int*   mark_cnt  = (int*)d_ws;
  int*   mark_rows = (int*)((char*)d_ws + 16);
  float* wd = (float*)((char*)d_ws + 16 + 4*MAXMARK);
  int*   wi = (int*)((char*)wd + (size_t)RP * 3 * 4);

  hipMemsetAsync(d_ws, 0, 16, stream);

  cls_head_kernel<<<(RC + 63) / 64, 64, 0, stream>>>(
      feats, cls_w1, cls_g, cls_b, cls_m, cls_v, cls_w2, cls_b2,
      (float*)d_out, RC);

  dim3 g1((NP + QPB - 1) / QPB, 1, B);
  knn_scan_kernel<<<g1, 256, 0, stream>>>(coords, pts, wd, wi,
                                          mark_cnt, mark_rows, NC, NP);

  tie_resort_kernel<<<MAXMARK, 256, 0, stream>>>(coords, pts, mark_cnt, mark_rows,
                                                 wd, wi, NC, NP);

  float* out2 = (float*)d_out + (size_t)RC * NCLS;
  interp_mlp_kernel<<<(RP + 63) / 64, 64, 0, stream>>>(
      feats, wd, wi,
      al_w, al_b, al_g, al_bb, al_m, al_v,
      o_w1, o_g, o_bb, o_m, o_v, o_w2, o_b2,
      out2, NC, NP, B);
}